// Round 4
// baseline (148.930 us; speedup 1.0000x reference)
//
#include <hip/hip_runtime.h>

static constexpr int OHW = 12, NSP = 144;

// ---------------------------------------------------------------------------
// build_T: gather x (4,256,14,14) -> T[n][k][i], n = b*144+oh*12+ow,
// k = (kh*3+kw)*32 + ic, i in [0,8). One float4 (4 consecutive i) per thread.
// (~4 us; fusing it into caps_main was tried and regressed phase 1 by 11 us.)
// ---------------------------------------------------------------------------
__global__ void build_T(const float* __restrict__ x, float4* __restrict__ T4) {
    const int g = blockIdx.x * 256 + threadIdx.x;   // [0, 576*576)
    const int n = g / 576;                          // 576 float4 per n
    const int q = g - n * 576;
    const int r = q << 2;                           // float offset in row
    const int k = r >> 3;
    const int i0 = r & 7;                           // 0 or 4
    const int ic = k & 31;
    const int kk = k >> 5;
    const int kh = kk / 3, kw = kk - kh * 3;
    const int b = n / NSP;
    const int rm = n - b * NSP;
    const int oh = rm / OHW, ow = rm - oh * OHW;
    const float* xp = x + (size_t)(b * 256 + ic * 8 + i0) * 196
                        + (oh + kh) * 14 + (ow + kw);
    float4 v;
    v.x = xp[0];
    v.y = xp[196];
    v.z = xp[392];
    v.w = xp[588];
    T4[g] = v;
}

__device__ __forceinline__ void fma4(float4& a, float s, const float4& w) {
    a.x = fmaf(s, w.x, a.x);
    a.y = fmaf(s, w.y, a.y);
    a.z = fmaf(s, w.z, a.z);
    a.w = fmaf(s, w.w, a.w);
}

__device__ __forceinline__ void add4(float4& a, const float4& b) {
    a.x += b.x; a.y += b.y; a.z += b.z; a.w += b.w;
}

__device__ __forceinline__ float4 shfl_xor4(const float4& v, int m) {
    float4 r;
    r.x = __shfl_xor(v.x, m);
    r.y = __shfl_xor(v.y, m);
    r.z = __shfl_xor(v.z, m);
    r.w = __shfl_xor(v.w, m);
    return r;
}

// Compute one k-slab (16 k x 4 c x 4 n): load w[8] once, produce 4 n's prior
// quads, write LDS. k = (lane>>2) + 16*g. LDS write address = const + lane
// (lane-consecutive, conflict-free b128). Slab stride in Pl is 9 (per-chunk).
__device__ __forceinline__ void do_j(const float4* __restrict__ T4,
                                     const float4* __restrict__ W4,
                                     float4* __restrict__ Pl,
                                     int o, int nbase, int k, int cg,
                                     int g_local, int lane) {
    float4 w[8];
    const float4* wp = W4 + (size_t)(o * 288 + k) * 32 + cg;
    #pragma unroll
    for (int i = 0; i < 8; ++i) w[i] = wp[i * 4];
    #pragma unroll
    for (int nn = 0; nn < 4; ++nn) {
        const float4* tp = T4 + (size_t)(nbase + nn) * 576 + k * 2;
        const float4 t0 = tp[0];
        const float4 t1 = tp[1];
        float4 a = make_float4(0.f, 0.f, 0.f, 0.f);
        fma4(a, t0.x, w[0]); fma4(a, t0.y, w[1]);
        fma4(a, t0.z, w[2]); fma4(a, t0.w, w[3]);
        fma4(a, t1.x, w[4]); fma4(a, t1.y, w[5]);
        fma4(a, t1.z, w[6]); fma4(a, t1.w, w[7]);
        Pl[nn * 576 + g_local * 64 + lane] = a;
    }
}

// ---------------------------------------------------------------------------
// caps_main: block = (o, 4 n's), 512 threads = 8 waves. Wave = (n_local,
// k_half): per-lane routing state is P[9] f4 = 36 regs (was 18 f4 = 72,
// which forced 64 VGPR + 64 AGPR = 128/wave -> 16 waves/CU cap; rounds 0-3
// showed occupancy pinned at 38% by exactly that). Target: 24 waves/CU via
// __launch_bounds__(512,6) (85-reg budget; peak live ~70, no spill).
// Phase 1: chunk0 = slabs 0-8 by all 8 waves (crit 2 do_j), khalf0 waves
// read their P; chunk1 = slabs 9-17 by khalf1 waves ONLY (crit 3) so khalf0
// never holds P[9] concurrently with do_j's ~55 live regs.
// Phase 2: intra-wave kgp-reduce (shfl 4..32) gives half-k sums; khalf pair
// exchanges svU/S through LDS (Pl reused) once per routing iteration.
// ---------------------------------------------------------------------------
__global__ __launch_bounds__(512, 6)
void caps_main(const float4* __restrict__ T4, const float4* __restrict__ W4,
               float* __restrict__ out) {
    __shared__ float4 Pl[4 * 9 * 64];   // 36,864 B; reused as exchange buf
    const int tid = threadIdx.x;
    const int o = blockIdx.y;
    const int nbase = blockIdx.x * 4;
    const int cg = tid & 3;
    const int lane = tid & 63;
    const int kgp = lane >> 2;          // [0,16)
    const int wv = tid >> 6;            // [0,8)
    const int nl = wv >> 1;             // n_local in [0,4)
    const int khf = wv & 1;             // k-half: slabs [9*khf, 9*khf+9)

    // ---- phase 1, chunk 0: slabs g in [0,9), all 8 waves ----
    do_j(T4, W4, Pl, o, nbase, kgp + 16 * wv, cg, wv, lane);
    if (wv == 0)
        do_j(T4, W4, Pl, o, nbase, kgp + 16 * 8, cg, 8, lane);
    __syncthreads();

    float4 P[9];
    if (khf == 0) {
        #pragma unroll
        for (int jj = 0; jj < 9; ++jj)
            P[jj] = Pl[nl * 576 + jj * 64 + lane];
    }
    __syncthreads();

    // ---- phase 1, chunk 1: slabs g in [9,18), khalf1 waves only ----
    if (khf == 1) {
        const int m = wv >> 1;
        do_j(T4, W4, Pl, o, nbase, kgp + 16 * (9 + m),  cg, m,     lane);
        do_j(T4, W4, Pl, o, nbase, kgp + 16 * (13 + m), cg, 4 + m, lane);
        if (m == 0)
            do_j(T4, W4, Pl, o, nbase, kgp + 16 * 17, cg, 8, lane);
    }
    __syncthreads();
    if (khf == 1) {
        #pragma unroll
        for (int jj = 0; jj < 9; ++jj)
            P[jj] = Pl[nl * 576 + jj * 64 + lane];
    }
    __syncthreads();   // all P reads done before Pl is reused below

    // exchange region carved out of Pl: svU f4 at [wv][lane], S after it
    float4* xb4 = Pl;                       // 8*64 f4 = 8 KB
    float*  xbS = (float*)(Pl + 512);       // 8*64 f  = 2 KB

    // ---- phase 2: dynamic routing; wave owns half the k-range of its n ----
    float lj[9];
    #pragma unroll
    for (int jj = 0; jj < 9; ++jj) lj[jj] = 0.f;
    float4 vq = make_float4(0.f, 0.f, 0.f, 0.f);

    #pragma unroll
    for (int it = 0; it < 3; ++it) {
        float4 svU = make_float4(0.f, 0.f, 0.f, 0.f);
        float S;
        if (it == 0) {
            #pragma unroll
            for (int jj = 0; jj < 9; ++jj) add4(svU, P[jj]);
            #pragma unroll
            for (int m = 4; m < 64; m <<= 1)
                { const float4 t = shfl_xor4(svU, m); add4(svU, t); }
            S = 288.0f;
        } else {
            S = 0.f;
            #pragma unroll
            for (int jj = 0; jj < 9; ++jj) {
                const float e = __expf(lj[jj]);   // |lj| small; no max needed
                S += e;
                fma4(svU, e, P[jj]);
            }
            #pragma unroll
            for (int m = 4; m < 64; m <<= 1) {
                const float4 t = shfl_xor4(svU, m);
                add4(svU, t);
                S += __shfl_xor(S, m);
            }
        }
        // cross-wave (k-half pair) combine via LDS
        xb4[wv * 64 + lane] = svU;
        if (it) xbS[wv * 64 + lane] = S;
        __syncthreads();
        add4(svU, xb4[(wv ^ 1) * 64 + lane]);
        if (it) S += xbS[(wv ^ 1) * 64 + lane];
        if (it < 2) __syncthreads();   // buffer safe before next it's write

        const float invS = __frcp_rn(S);
        float4 s;
        s.x = svU.x * invS; s.y = svU.y * invS;
        s.z = svU.z * invS; s.w = svU.w * invS;
        float sq = s.x * s.x + s.y * s.y + s.z * s.z + s.w * s.w;
        sq += __shfl_xor(sq, 1);
        sq += __shfl_xor(sq, 2);
        const float scale = __fsqrt_rn(sq) / (1.0f + sq);
        vq.x = s.x * scale; vq.y = s.y * scale;
        vq.z = s.z * scale; vq.w = s.w * scale;

        if (it < 2) {
            #pragma unroll
            for (int jj = 0; jj < 9; ++jj) {
                float d = P[jj].x * vq.x + P[jj].y * vq.y +
                          P[jj].z * vq.z + P[jj].w * vq.w;
                d += __shfl_xor(d, 1);
                d += __shfl_xor(d, 2);
                lj[jj] += d;
            }
        }
    }

    // ---- store: khalf0 waves, lanes kgp==0 write their c-quad ----
    if (khf == 0 && kgp == 0) {
        const int n = nbase + nl;
        const int b = n / NSP;
        const int rm = n - b * NSP;
        float* op = out + (size_t)(b * 512 + o * 16 + cg * 4) * NSP + rm;
        op[0 * NSP] = vq.x;
        op[1 * NSP] = vq.y;
        op[2 * NSP] = vq.z;
        op[3 * NSP] = vq.w;
    }
}

extern "C" void kernel_launch(void* const* d_in, const int* in_sizes, int n_in,
                              void* d_out, int out_size, void* d_ws, size_t ws_size,
                              hipStream_t stream) {
    const float* x  = (const float*)d_in[0];   // (4, 256, 14, 14)
    const float* wt = (const float*)d_in[1];   // (32, 288, 8, 16)
    float* out = (float*)d_out;                // (4, 512, 12, 12)
    float4* T4 = (float4*)d_ws;                // 576*2304 floats = 5.3 MB

    build_T<<<dim3(576 * 576 / 256), 256, 0, stream>>>(x, T4);
    caps_main<<<dim3(144, 32), 512, 0, stream>>>(T4, (const float4*)wt, out);
}